// Round 9
// baseline (201.409 us; speedup 1.0000x reference)
//
#include <hip/hip_runtime.h>
#include <cstdint>
#include <cstddef>

#define N_EMBD 1024
#define T_SEQ  2048
#define NBATCH 4
#define SPAN   256
#define C3     3072
// scale = sqrt(N_EMBD * SPAN) = 512

typedef float  floatx4 __attribute__((ext_vector_type(4)));
typedef __bf16 bf16x8  __attribute__((ext_vector_type(8)));

__device__ inline unsigned short f2bf(float f) {
    union { float f; unsigned u; } x; x.f = f;
    unsigned u = x.u;
    unsigned r = (u + 0x7fffu + ((u >> 16) & 1u)) >> 16;
    return (unsigned short)r;
}

typedef __attribute__((address_space(1))) const void GVOID;
typedef __attribute__((address_space(3))) void LVOID;
__device__ inline void gl2lds16(const void* g, void* l) {
    __builtin_amdgcn_global_load_lds((GVOID*)g, (LVOID*)l, 16, 0, 0);
}

// --- swizzled staging helpers -----------------------------------------------
// 128 rows x 32 cols bf16. LDS chunk slot c of row r holds global chunk c^((r>>1)&3).
// Reader chunk offset: qk = ((lane>>4) ^ ((lane>>1)&3)) * 8.
__device__ inline void stage128x32(const unsigned short* g, size_t stride,
                                   unsigned short* lds, int lane, int wave) {
    const int r     = wave * 16 + (lane >> 2);
    const int chunk = (lane & 3) ^ ((r >> 1) & 3);
    const unsigned short* src = g + (size_t)r * stride + chunk * 8;
    gl2lds16(src,               &lds[(wave * 16) * 32]);
    gl2lds16(src + 64 * stride, &lds[(64 + wave * 16) * 32]);
}

// 64 rows x 64 cols bf16, 256-thread WG. Slot c of row r holds global chunk c^(r&7).
__device__ inline void stage64x64(const unsigned short* g, size_t stride,
                                  unsigned short* lds, int lane, int wave) {
#pragma unroll
    for (int rnd = 0; rnd < 2; rnd++) {
        const int r = rnd * 32 + wave * 8 + (lane >> 3);
        const int chunk = (lane & 7) ^ (r & 7);
        gl2lds16(g + (size_t)r * stride + chunk * 8, &lds[(rnd * 32 + wave * 8) * 64]);
    }
}

// 128 rows x 64 cols bf16. 4 rounds.
__device__ inline void stage128x64(const unsigned short* g, size_t stride,
                                   unsigned short* lds, int lane, int wave) {
#pragma unroll
    for (int rnd = 0; rnd < 4; rnd++) {
        const int r = rnd * 32 + wave * 8 + (lane >> 3);
        const int chunk = (lane & 7) ^ (r & 7);
        gl2lds16(g + (size_t)r * stride + chunk * 8, &lds[(rnd * 32 + wave * 8) * 64]);
    }
}

// ---------------------------------------------------------------------------
// K0: fused conversions. blocks [0,8192): x fp32->bf16. blocks [8192,11264): W -> WbT.
__global__ __launch_bounds__(256) void k_prep(const float* __restrict__ x,
                                              unsigned short* __restrict__ Xb,
                                              const float* __restrict__ W,
                                              unsigned short* __restrict__ WbT) {
    __shared__ unsigned short t[32][33];
    if (blockIdx.x < 8192) {
        int i = (blockIdx.x * 256 + threadIdx.x) * 4;
        float4 v = *(const float4*)(x + i);
        ushort4 o;
        o.x = f2bf(v.x); o.y = f2bf(v.y); o.z = f2bf(v.z); o.w = f2bf(v.w);
        *(ushort4*)(Xb + i) = o;
    } else {
        int bid = blockIdx.x - 8192;
        int k0 = (bid & 31) * 32, n0 = (bid >> 5) * 32;
        int tx = threadIdx.x & 31, ty = threadIdx.x >> 5;
#pragma unroll
        for (int i = 0; i < 4; i++) {
            int k = k0 + ty + i * 8;
            t[ty + i * 8][tx] = f2bf(W[(size_t)k * C3 + n0 + tx]);
        }
        __syncthreads();
#pragma unroll
        for (int i = 0; i < 4; i++) {
            int n = n0 + ty + i * 8;
            WbT[(size_t)n * N_EMBD + k0 + tx] = t[tx][ty + i * 8];
        }
    }
}

// ---------------------------------------------------------------------------
// K1: unified QKV GEMM, 128x128 tile, BK=32, 16 KB LDS, grid 24x64.
// EXACT r0/r4 version (71.4 us, MfmaUtil 29.5, ~2.3-3 WGs/CU). CLOSED:
// r2/r3 8-phase & fat-phase (87-97us), r8 BK=64 (74.9us, VALUBusy 2x,
// occupancy -9), r7 XCD swizzle (FETCH -20% but +1us index math) all
// neutral-to-worse. This IS the m97 structure (16 MFMA + 2 gl2lds/iter);
// remaining gap to 874TF is K=1024 shape amortization, not tunable.
__global__ __launch_bounds__(256) void k_gemm(const unsigned short* __restrict__ Xb,
                                              const unsigned short* __restrict__ WbT,
                                              const float* __restrict__ bqkv,
                                              unsigned short* __restrict__ QK,
                                              unsigned short* __restrict__ Vt) {
    __shared__ unsigned short As[4096];
    __shared__ unsigned short Bs[4096];
    const int tid = threadIdx.x, lane = tid & 63, wave = tid >> 6;
    const int bx = blockIdx.x, m0 = blockIdx.y * 128;
    const bool isV = (bx >= 16);
    const int n0 = isV ? (2048 + (bx - 16) * 128) : (bx * 128);
    const int wr = wave >> 1, wc = wave & 1;

    floatx4 acc[4][4] = {};

    const unsigned short* gA = (isV ? WbT + (size_t)n0 * N_EMBD : Xb  + (size_t)m0 * N_EMBD);
    const unsigned short* gB = (isV ? Xb  + (size_t)m0 * N_EMBD : WbT + (size_t)n0 * N_EMBD);
    const int qk = ((lane >> 4) ^ ((lane >> 1) & 3)) * 8;
    const int ra = wr * 64 + (lane & 15);
    const int rb = wc * 64 + (lane & 15);

    for (int k0 = 0; k0 < N_EMBD; k0 += 32) {
        stage128x32(gA + k0, N_EMBD, As, lane, wave);
        stage128x32(gB + k0, N_EMBD, Bs, lane, wave);
        __syncthreads();
        bf16x8 a[4], b[4];
#pragma unroll
        for (int mi = 0; mi < 4; mi++) a[mi] = *(const bf16x8*)&As[(ra + mi * 16) * 32 + qk];
#pragma unroll
        for (int ni = 0; ni < 4; ni++) b[ni] = *(const bf16x8*)&Bs[(rb + ni * 16) * 32 + qk];
#pragma unroll
        for (int mi = 0; mi < 4; mi++)
#pragma unroll
            for (int ni = 0; ni < 4; ni++)
                acc[mi][ni] = __builtin_amdgcn_mfma_f32_16x16x32_bf16(a[mi], b[ni], acc[mi][ni], 0, 0, 0);
        __syncthreads();
    }

    // Unified epilogue.
    const int cn = lane & 15, q = lane >> 4;
    unsigned short* base = isV ? Vt : QK;
    const int rowbase = isV ? (((m0 >> 11) << 10) + (n0 - 2048)) : m0;
    const int colbase = isV ? (m0 & 2047) : n0;
#pragma unroll
    for (int mi = 0; mi < 4; mi++) {
#pragma unroll
        for (int r = 0; r < 4; r++) {
            const int arow = wr * 64 + mi * 16 + q * 4 + r;
            unsigned short* dst = base + (size_t)(rowbase + arow) * 2048 + colbase;
#pragma unroll
            for (int ni = 0; ni < 4; ni++) {
                const int acol = wc * 64 + ni * 16 + cn;
                const float bias = bqkv[n0 + (isV ? arow : acol)];
                dst[acol] = f2bf(acc[mi][ni][r] + bias);
            }
        }
    }
}

// ---------------------------------------------------------------------------
// K2: banded scores, 64x64 out tiles, BK=128 (2 k-steps per barrier-pair).
// 640 WGs 1D, XCD-chunked swizzle (chunk=80). EXACT r4 version (195.8 us best).
// r7 lesson: jj-pairing at 384 WGs = 1.5 WGs/CU grid-quantization loss.
// S block layout: [(b*32+qb)*5+jj] -> 64x64 bf16 row-major.
__global__ __launch_bounds__(256) void k_scores(const unsigned short* __restrict__ QK,
                                                unsigned short* __restrict__ S) {
    const int logical = (blockIdx.x & 7) * 80 + (blockIdx.x >> 3);
    const int jj = logical % 5;
    const int qb = (logical / 5) & 31;
    const int b  = logical / 160;
    const int jb = qb - 4 + jj;
    if (jb < 0) return;

    __shared__ unsigned short Qs[2][4096];
    __shared__ unsigned short Ks[2][4096];
    const int tid = threadIdx.x, lane = tid & 63, wave = tid >> 6;
    const int wr = wave >> 1, wc = wave & 1;
    const int n15 = lane & 15, q = lane >> 4;

    floatx4 acc[2][2] = {};

    const unsigned short* gQ = QK + ((size_t)(b * T_SEQ + qb * 64)) * 2048;
    const unsigned short* gK = QK + ((size_t)(b * T_SEQ + jb * 64)) * 2048 + 1024;

    for (int k0 = 0; k0 < N_EMBD; k0 += 128) {
        stage64x64(gQ + k0,      2048, Qs[0], lane, wave);
        stage64x64(gQ + k0 + 64, 2048, Qs[1], lane, wave);
        stage64x64(gK + k0,      2048, Ks[0], lane, wave);
        stage64x64(gK + k0 + 64, 2048, Ks[1], lane, wave);
        __syncthreads();
#pragma unroll
        for (int h = 0; h < 2; h++) {
#pragma unroll
            for (int s = 0; s < 2; s++) {
                bf16x8 a[2], bbf[2];
#pragma unroll
                for (int mi = 0; mi < 2; mi++) {
                    const int row = wr * 32 + mi * 16 + n15;
                    a[mi] = *(const bf16x8*)&Qs[h][row * 64 + (((s * 4 + q) ^ (row & 7)) * 8)];
                }
#pragma unroll
                for (int ni = 0; ni < 2; ni++) {
                    const int row = wc * 32 + ni * 16 + n15;
                    bbf[ni] = *(const bf16x8*)&Ks[h][row * 64 + (((s * 4 + q) ^ (row & 7)) * 8)];
                }
#pragma unroll
                for (int mi = 0; mi < 2; mi++)
#pragma unroll
                    for (int ni = 0; ni < 2; ni++)
                        acc[mi][ni] = __builtin_amdgcn_mfma_f32_16x16x32_bf16(a[mi], bbf[ni], acc[mi][ni], 0, 0, 0);
            }
        }
        __syncthreads();
    }

    unsigned short* Sb = S + (((size_t)(b * 32 + qb) * 5 + jj) << 12);
#pragma unroll
    for (int mi = 0; mi < 2; mi++)
#pragma unroll
        for (int ni = 0; ni < 2; ni++)
#pragma unroll
            for (int r = 0; r < 4; r++) {
                const int il = wr * 32 + mi * 16 + q * 4 + r;
                const int jl = wc * 32 + ni * 16 + n15;
                const int gi = qb * 64 + il, gj = jb * 64 + jl;
                const float v = ((gj <= gi) && (gj > gi - SPAN)) ? acc[mi][ni][r] * (1.0f / 512.0f) : 0.0f;
                Sb[il * 64 + jl] = f2bf(v);
            }
}

// ---------------------------------------------------------------------------
// K3: out[64 x 128] = sum_jj S(64x64) @ V(64x128). 1024 WGs 1D, XCD-chunked
// swizzle (chunk=128): all 8 cg-WGs of a qb share one XCD -> S L2-hot.
// r9 change vs r4: S a-frags read DIRECT from global (swizzle algebra:
// staged LDS slot c^(r&7) read back with the same XOR == linear global read
// at row*64 + (s*4+q)*8 — bit-identical bytes). Removes 2 staged loads/thread
// per jj + 4 ds_read/(t,s); LDS 48->32 KB -> occupancy 3->4 WGs/CU.
// V staging + barrier structure + MFMA order unchanged.
__global__ __launch_bounds__(256) void k_sv(const unsigned short* __restrict__ S,
                                            const unsigned short* __restrict__ Vt,
                                            float* __restrict__ out) {
    const int logical = (blockIdx.x & 7) * 128 + (blockIdx.x >> 3);
    const int cg = logical & 7;
    const int qb = (logical >> 3) & 31;
    const int b  = logical >> 8;
    const int c0 = cg * 128;

    __shared__ unsigned short Vs[2][8192];   // 32 KB
    const int tid = threadIdx.x, lane = tid & 63, wave = tid >> 6;
    const int wr = wave >> 1, wc = wave & 1;
    const int n15 = lane & 15, q = lane >> 4;

    floatx4 acc[2][4] = {};

    const size_t vbase = ((size_t)(b * 1024 + c0)) * 2048;
    const unsigned short* Sg = S + (((size_t)(b * 32 + qb) * 5) << 12);

    for (int j0 = 0; j0 < 5; j0 += 2) {
        const int nv = (j0 < 4) ? 2 : 1;
        bool val[2] = {false, false};
#pragma unroll
        for (int t = 0; t < 2; t++) {
            if (t < nv && (qb - 4 + j0 + t) >= 0) {
                val[t] = true;
                stage128x64(Vt + vbase + (size_t)(qb - 4 + j0 + t) * 64, 2048, Vs[t], lane, wave);
            }
        }
        __syncthreads();
#pragma unroll
        for (int t = 0; t < 2; t++) {
            if (!val[t]) continue;
            const unsigned short* Sb = Sg + ((size_t)(j0 + t) << 12);
#pragma unroll
            for (int s = 0; s < 2; s++) {
                bf16x8 a[2], bbf[4];
#pragma unroll
                for (int mi = 0; mi < 2; mi++) {
                    const int row = wr * 32 + mi * 16 + n15;
                    a[mi] = *(const bf16x8*)&Sb[row * 64 + (s * 4 + q) * 8];
                }
#pragma unroll
                for (int ni = 0; ni < 4; ni++) {
                    const int row = wc * 64 + ni * 16 + n15;
                    bbf[ni] = *(const bf16x8*)&Vs[t][row * 64 + (((s * 4 + q) ^ (row & 7)) * 8)];
                }
#pragma unroll
                for (int mi = 0; mi < 2; mi++)
#pragma unroll
                    for (int ni = 0; ni < 4; ni++)
                        acc[mi][ni] = __builtin_amdgcn_mfma_f32_16x16x32_bf16(a[mi], bbf[ni], acc[mi][ni], 0, 0, 0);
            }
        }
        __syncthreads();
    }

#pragma unroll
    for (int mi = 0; mi < 2; mi++)
#pragma unroll
        for (int ni = 0; ni < 4; ni++)
#pragma unroll
            for (int r = 0; r < 4; r++) {
                const int il = wr * 32 + mi * 16 + q * 4 + r;
                const int cl = wc * 64 + ni * 16 + n15;
                out[((size_t)(b * T_SEQ + qb * 64 + il)) * N_EMBD + c0 + cl] = acc[mi][ni][r];
            }
}

// ---------------------------------------------------------------------------
// K4: in-place LayerNorm over last dim (1024), one WG per row
__global__ __launch_bounds__(256) void k_ln(float* __restrict__ out,
                                            const float* __restrict__ w,
                                            const float* __restrict__ bias) {
    __shared__ float red[8];
    const int t = threadIdx.x;
    float* p = out + (size_t)blockIdx.x * N_EMBD;
    float4 v = ((const float4*)p)[t];
    float s  = v.x + v.y + v.z + v.w;
    float sq = v.x * v.x + v.y * v.y + v.z * v.z + v.w * v.w;
#pragma unroll
    for (int off = 32; off; off >>= 1) {
        s  += __shfl_down(s, off, 64);
        sq += __shfl_down(sq, off, 64);
    }
    const int wave = t >> 6, lane = t & 63;
    if (lane == 0) { red[wave] = s; red[4 + wave] = sq; }
    __syncthreads();
    const float ts = red[0] + red[1] + red[2] + red[3];
    const float tq = red[4] + red[5] + red[6] + red[7];
    const float mean = ts * (1.0f / N_EMBD);
    const float var  = tq * (1.0f / N_EMBD) - mean * mean;
    const float rs = rsqrtf(var + 1e-5f);
    float4 wv = ((const float4*)w)[t];
    float4 bv = ((const float4*)bias)[t];
    float4 o;
    o.x = (v.x - mean) * rs * wv.x + bv.x;
    o.y = (v.y - mean) * rs * wv.y + bv.y;
    o.z = (v.z - mean) * rs * wv.z + bv.z;
    o.w = (v.w - mean) * rs * wv.w + bv.w;
    ((float4*)p)[t] = o;
}

// ---------------------------------------------------------------------------
extern "C" void kernel_launch(void* const* d_in, const int* in_sizes, int n_in,
                              void* d_out, int out_size, void* d_ws, size_t ws_size,
                              hipStream_t stream) {
    const float* x  = (const float*)d_in[0];
    const float* W  = (const float*)d_in[1];
    const float* bq = (const float*)d_in[2];
    const float* lw = (const float*)d_in[3];
    const float* lb = (const float*)d_in[4];
    float* out = (float*)d_out;
    char* ws = (char*)d_ws;

    // workspace layout (bytes):
    //  Xb   @ 0          16,777,216  (8192x1024 bf16) — dead after GEMM
    //  Sbuf @ 0           5,242,880  (4*32*5 blocks of 64x64 bf16) — aliases Xb
    //  WbT  @ 16,777,216  6,291,456  (3072x1024 bf16)
    //  QK   @ 23,068,672 33,554,432  (8192x2048 bf16)
    //  Vt   @ 56,623,104 16,777,216  (4x1024x2048 bf16)
    //  total 73,400,320
    unsigned short* Xb   = (unsigned short*)(ws + 0);
    unsigned short* Sbuf = (unsigned short*)(ws + 0);
    unsigned short* WbT  = (unsigned short*)(ws + 16777216);
    unsigned short* QK   = (unsigned short*)(ws + 23068672);
    unsigned short* Vt   = (unsigned short*)(ws + 56623104);

    k_prep   <<<11264,        256, 0, stream>>>(x, Xb, W, WbT);
    k_gemm   <<<dim3(24, 64), 256, 0, stream>>>(Xb, WbT, bq, QK, Vt);
    k_scores <<<640,          256, 0, stream>>>(QK, Sbuf);
    k_sv     <<<1024,         256, 0, stream>>>(Sbuf, Vt, out);
    k_ln     <<<8192,         256, 0, stream>>>(out, lw, lb);
}

// Round 10
// 192.504 us; speedup vs baseline: 1.0463x; 1.0463x over previous
//
#include <hip/hip_runtime.h>
#include <cstdint>
#include <cstddef>

#define N_EMBD 1024
#define T_SEQ  2048
#define NBATCH 4
#define SPAN   256
#define C3     3072
// scale = sqrt(N_EMBD * SPAN) = 512

typedef float  floatx4 __attribute__((ext_vector_type(4)));
typedef __bf16 bf16x8  __attribute__((ext_vector_type(8)));

__device__ inline unsigned short f2bf(float f) {
    union { float f; unsigned u; } x; x.f = f;
    unsigned u = x.u;
    unsigned r = (u + 0x7fffu + ((u >> 16) & 1u)) >> 16;
    return (unsigned short)r;
}

typedef __attribute__((address_space(1))) const void GVOID;
typedef __attribute__((address_space(3))) void LVOID;
__device__ inline void gl2lds16(const void* g, void* l) {
    __builtin_amdgcn_global_load_lds((GVOID*)g, (LVOID*)l, 16, 0, 0);
}

// --- swizzled staging helpers -----------------------------------------------
// 128 rows x 32 cols bf16. LDS chunk slot c of row r holds global chunk c^((r>>1)&3).
// Reader chunk offset: qk = ((lane>>4) ^ ((lane>>1)&3)) * 8.
__device__ inline void stage128x32(const unsigned short* g, size_t stride,
                                   unsigned short* lds, int lane, int wave) {
    const int r     = wave * 16 + (lane >> 2);
    const int chunk = (lane & 3) ^ ((r >> 1) & 3);
    const unsigned short* src = g + (size_t)r * stride + chunk * 8;
    gl2lds16(src,               &lds[(wave * 16) * 32]);
    gl2lds16(src + 64 * stride, &lds[(64 + wave * 16) * 32]);
}

// 64 rows x 64 cols bf16. Slot c of row r holds global chunk c^(r&7). 2 rounds.
__device__ inline void stage64x64(const unsigned short* g, size_t stride,
                                  unsigned short* lds, int lane, int wave) {
#pragma unroll
    for (int rnd = 0; rnd < 2; rnd++) {
        const int r = rnd * 32 + wave * 8 + (lane >> 3);
        const int chunk = (lane & 7) ^ (r & 7);
        gl2lds16(g + (size_t)r * stride + chunk * 8, &lds[(rnd * 32 + wave * 8) * 64]);
    }
}

// 128 rows x 64 cols bf16. 4 rounds.
__device__ inline void stage128x64(const unsigned short* g, size_t stride,
                                   unsigned short* lds, int lane, int wave) {
#pragma unroll
    for (int rnd = 0; rnd < 4; rnd++) {
        const int r = rnd * 32 + wave * 8 + (lane >> 3);
        const int chunk = (lane & 7) ^ (r & 7);
        gl2lds16(g + (size_t)r * stride + chunk * 8, &lds[(rnd * 32 + wave * 8) * 64]);
    }
}

// ---------------------------------------------------------------------------
// K0: fused conversions. blocks [0,8192): x fp32->bf16. blocks [8192,11264): W -> WbT.
__global__ __launch_bounds__(256) void k_prep(const float* __restrict__ x,
                                              unsigned short* __restrict__ Xb,
                                              const float* __restrict__ W,
                                              unsigned short* __restrict__ WbT) {
    __shared__ unsigned short t[32][33];
    if (blockIdx.x < 8192) {
        int i = (blockIdx.x * 256 + threadIdx.x) * 4;
        float4 v = *(const float4*)(x + i);
        ushort4 o;
        o.x = f2bf(v.x); o.y = f2bf(v.y); o.z = f2bf(v.z); o.w = f2bf(v.w);
        *(ushort4*)(Xb + i) = o;
    } else {
        int bid = blockIdx.x - 8192;
        int k0 = (bid & 31) * 32, n0 = (bid >> 5) * 32;
        int tx = threadIdx.x & 31, ty = threadIdx.x >> 5;
#pragma unroll
        for (int i = 0; i < 4; i++) {
            int k = k0 + ty + i * 8;
            t[ty + i * 8][tx] = f2bf(W[(size_t)k * C3 + n0 + tx]);
        }
        __syncthreads();
#pragma unroll
        for (int i = 0; i < 4; i++) {
            int n = n0 + ty + i * 8;
            WbT[(size_t)n * N_EMBD + k0 + tx] = t[tx][ty + i * 8];
        }
    }
}

// ---------------------------------------------------------------------------
// K1: unified QKV GEMM, 128x128 tile, BK=32, 16 KB LDS, grid 24x64.
// EXACT r0 version (71.4 us, MfmaUtil 29.5, ~3 WGs/CU). CLOSED after 6
// structural variants: 8-phase (96.8), fat-phase (87.2), BK=64 (74.9,
// VALUBusy 2x, occupancy -9), XCD swizzle (FETCH -20%, time-neutral),
// min-waves launch_bounds (4.4x worse), 1-WG/CU fusions (worse). This IS
// the m97 structure (16 MFMA + 2 gl2lds/iter); residency does the latency
// hiding — do not trade it away.
__global__ __launch_bounds__(256) void k_gemm(const unsigned short* __restrict__ Xb,
                                              const unsigned short* __restrict__ WbT,
                                              const float* __restrict__ bqkv,
                                              unsigned short* __restrict__ QK,
                                              unsigned short* __restrict__ Vt) {
    __shared__ unsigned short As[4096];
    __shared__ unsigned short Bs[4096];
    const int tid = threadIdx.x, lane = tid & 63, wave = tid >> 6;
    const int bx = blockIdx.x, m0 = blockIdx.y * 128;
    const bool isV = (bx >= 16);
    const int n0 = isV ? (2048 + (bx - 16) * 128) : (bx * 128);
    const int wr = wave >> 1, wc = wave & 1;

    floatx4 acc[4][4] = {};

    const unsigned short* gA = (isV ? WbT + (size_t)n0 * N_EMBD : Xb  + (size_t)m0 * N_EMBD);
    const unsigned short* gB = (isV ? Xb  + (size_t)m0 * N_EMBD : WbT + (size_t)n0 * N_EMBD);
    const int qk = ((lane >> 4) ^ ((lane >> 1) & 3)) * 8;
    const int ra = wr * 64 + (lane & 15);
    const int rb = wc * 64 + (lane & 15);

    for (int k0 = 0; k0 < N_EMBD; k0 += 32) {
        stage128x32(gA + k0, N_EMBD, As, lane, wave);
        stage128x32(gB + k0, N_EMBD, Bs, lane, wave);
        __syncthreads();
        bf16x8 a[4], b[4];
#pragma unroll
        for (int mi = 0; mi < 4; mi++) a[mi] = *(const bf16x8*)&As[(ra + mi * 16) * 32 + qk];
#pragma unroll
        for (int ni = 0; ni < 4; ni++) b[ni] = *(const bf16x8*)&Bs[(rb + ni * 16) * 32 + qk];
#pragma unroll
        for (int mi = 0; mi < 4; mi++)
#pragma unroll
            for (int ni = 0; ni < 4; ni++)
                acc[mi][ni] = __builtin_amdgcn_mfma_f32_16x16x32_bf16(a[mi], b[ni], acc[mi][ni], 0, 0, 0);
        __syncthreads();
    }

    // Unified epilogue.
    const int cn = lane & 15, q = lane >> 4;
    unsigned short* base = isV ? Vt : QK;
    const int rowbase = isV ? (((m0 >> 11) << 10) + (n0 - 2048)) : m0;
    const int colbase = isV ? (m0 & 2047) : n0;
#pragma unroll
    for (int mi = 0; mi < 4; mi++) {
#pragma unroll
        for (int r = 0; r < 4; r++) {
            const int arow = wr * 64 + mi * 16 + q * 4 + r;
            unsigned short* dst = base + (size_t)(rowbase + arow) * 2048 + colbase;
#pragma unroll
            for (int ni = 0; ni < 4; ni++) {
                const int acol = wc * 64 + ni * 16 + cn;
                const float bias = bqkv[n0 + (isV ? arow : acol)];
                dst[acol] = f2bf(acc[mi][ni][r] + bias);
            }
        }
    }
}

// ---------------------------------------------------------------------------
// K2: banded scores, 64x64 out tiles, BK=128 (2 k-steps per barrier-pair).
// 640 WGs 1D, XCD-chunked swizzle (chunk=80): the 5 jj-WGs of a qb share an
// XCD, and the chunk map matches k_sv's (both (b,qb)->xcd = b*2 + (qb>=16))
// so S hands off L2-locally. EXACT r4 version (195.8 us best).
// r7 lesson: jj-pairing at 384 WGs = 1.5 WGs/CU grid-quantization loss.
__global__ __launch_bounds__(256) void k_scores(const unsigned short* __restrict__ QK,
                                                unsigned short* __restrict__ S) {
    const int logical = (blockIdx.x & 7) * 80 + (blockIdx.x >> 3);
    const int jj = logical % 5;
    const int qb = (logical / 5) & 31;
    const int b  = logical / 160;
    const int jb = qb - 4 + jj;
    if (jb < 0) return;

    __shared__ unsigned short Qs[2][4096];
    __shared__ unsigned short Ks[2][4096];
    const int tid = threadIdx.x, lane = tid & 63, wave = tid >> 6;
    const int wr = wave >> 1, wc = wave & 1;
    const int n15 = lane & 15, q = lane >> 4;

    floatx4 acc[2][2] = {};

    const unsigned short* gQ = QK + ((size_t)(b * T_SEQ + qb * 64)) * 2048;
    const unsigned short* gK = QK + ((size_t)(b * T_SEQ + jb * 64)) * 2048 + 1024;

    for (int k0 = 0; k0 < N_EMBD; k0 += 128) {
        stage64x64(gQ + k0,      2048, Qs[0], lane, wave);
        stage64x64(gQ + k0 + 64, 2048, Qs[1], lane, wave);
        stage64x64(gK + k0,      2048, Ks[0], lane, wave);
        stage64x64(gK + k0 + 64, 2048, Ks[1], lane, wave);
        __syncthreads();
#pragma unroll
        for (int h = 0; h < 2; h++) {
#pragma unroll
            for (int s = 0; s < 2; s++) {
                bf16x8 a[2], bbf[2];
#pragma unroll
                for (int mi = 0; mi < 2; mi++) {
                    const int row = wr * 32 + mi * 16 + n15;
                    a[mi] = *(const bf16x8*)&Qs[h][row * 64 + (((s * 4 + q) ^ (row & 7)) * 8)];
                }
#pragma unroll
                for (int ni = 0; ni < 2; ni++) {
                    const int row = wc * 32 + ni * 16 + n15;
                    bbf[ni] = *(const bf16x8*)&Ks[h][row * 64 + (((s * 4 + q) ^ (row & 7)) * 8)];
                }
#pragma unroll
                for (int mi = 0; mi < 2; mi++)
#pragma unroll
                    for (int ni = 0; ni < 2; ni++)
                        acc[mi][ni] = __builtin_amdgcn_mfma_f32_16x16x32_bf16(a[mi], bbf[ni], acc[mi][ni], 0, 0, 0);
            }
        }
        __syncthreads();
    }

    unsigned short* Sb = S + (((size_t)(b * 32 + qb) * 5 + jj) << 12);
#pragma unroll
    for (int mi = 0; mi < 2; mi++)
#pragma unroll
        for (int ni = 0; ni < 2; ni++)
#pragma unroll
            for (int r = 0; r < 4; r++) {
                const int il = wr * 32 + mi * 16 + q * 4 + r;
                const int jl = wc * 32 + ni * 16 + n15;
                const int gi = qb * 64 + il, gj = jb * 64 + jl;
                const float v = ((gj <= gi) && (gj > gi - SPAN)) ? acc[mi][ni][r] * (1.0f / 512.0f) : 0.0f;
                Sb[il * 64 + jl] = f2bf(v);
            }
}

// ---------------------------------------------------------------------------
// K3: out[64 x 128] = sum_jj S(64x64) @ V(64x128). 1024 WGs 1D, XCD-chunked
// swizzle (chunk=128). jj-tiles processed in pairs per barrier-pair.
// EXACT r4 version. r9 lesson: direct-global S reads (bit-identical bytes)
// cost ~5 us — 16B scattered L2 loads at 4 WGs/CU don't beat staged ds_read.
__global__ __launch_bounds__(256) void k_sv(const unsigned short* __restrict__ S,
                                            const unsigned short* __restrict__ Vt,
                                            float* __restrict__ out) {
    const int logical = (blockIdx.x & 7) * 128 + (blockIdx.x >> 3);
    const int cg = logical & 7;
    const int qb = (logical >> 3) & 31;
    const int b  = logical >> 8;
    const int c0 = cg * 128;

    __shared__ unsigned short Ss[2][4096];
    __shared__ unsigned short Vs[2][8192];
    const int tid = threadIdx.x, lane = tid & 63, wave = tid >> 6;
    const int wr = wave >> 1, wc = wave & 1;
    const int n15 = lane & 15, q = lane >> 4;

    floatx4 acc[2][4] = {};

    const size_t vbase = ((size_t)(b * 1024 + c0)) * 2048;
    const size_t sbase = ((size_t)(b * 32 + qb) * 5) << 12;

    for (int j0 = 0; j0 < 5; j0 += 2) {
        const int nv = (j0 < 4) ? 2 : 1;
        bool val[2] = {false, false};
#pragma unroll
        for (int t = 0; t < 2; t++) {
            if (t < nv && (qb - 4 + j0 + t) >= 0) {
                val[t] = true;
                stage64x64 (S + sbase + ((size_t)(j0 + t) << 12), 64, Ss[t], lane, wave);
                stage128x64(Vt + vbase + (size_t)(qb - 4 + j0 + t) * 64, 2048, Vs[t], lane, wave);
            }
        }
        __syncthreads();
#pragma unroll
        for (int t = 0; t < 2; t++) {
            if (!val[t]) continue;
#pragma unroll
            for (int s = 0; s < 2; s++) {
                bf16x8 a[2], bbf[4];
#pragma unroll
                for (int mi = 0; mi < 2; mi++) {
                    const int row = wr * 32 + mi * 16 + n15;
                    a[mi] = *(const bf16x8*)&Ss[t][row * 64 + (((s * 4 + q) ^ (row & 7)) * 8)];
                }
#pragma unroll
                for (int ni = 0; ni < 4; ni++) {
                    const int row = wc * 64 + ni * 16 + n15;
                    bbf[ni] = *(const bf16x8*)&Vs[t][row * 64 + (((s * 4 + q) ^ (row & 7)) * 8)];
                }
#pragma unroll
                for (int mi = 0; mi < 2; mi++)
#pragma unroll
                    for (int ni = 0; ni < 4; ni++)
                        acc[mi][ni] = __builtin_amdgcn_mfma_f32_16x16x32_bf16(a[mi], bbf[ni], acc[mi][ni], 0, 0, 0);
            }
        }
        __syncthreads();
    }

#pragma unroll
    for (int mi = 0; mi < 2; mi++)
#pragma unroll
        for (int ni = 0; ni < 4; ni++)
#pragma unroll
            for (int r = 0; r < 4; r++) {
                const int il = wr * 32 + mi * 16 + q * 4 + r;
                const int cl = wc * 64 + ni * 16 + n15;
                out[((size_t)(b * T_SEQ + qb * 64 + il)) * N_EMBD + c0 + cl] = acc[mi][ni][r];
            }
}

// ---------------------------------------------------------------------------
// K4: in-place LayerNorm over last dim (1024), one WG per row
__global__ __launch_bounds__(256) void k_ln(float* __restrict__ out,
                                            const float* __restrict__ w,
                                            const float* __restrict__ bias) {
    __shared__ float red[8];
    const int t = threadIdx.x;
    float* p = out + (size_t)blockIdx.x * N_EMBD;
    float4 v = ((const float4*)p)[t];
    float s  = v.x + v.y + v.z + v.w;
    float sq = v.x * v.x + v.y * v.y + v.z * v.z + v.w * v.w;
#pragma unroll
    for (int off = 32; off; off >>= 1) {
        s  += __shfl_down(s, off, 64);
        sq += __shfl_down(sq, off, 64);
    }
    const int wave = t >> 6, lane = t & 63;
    if (lane == 0) { red[wave] = s; red[4 + wave] = sq; }
    __syncthreads();
    const float ts = red[0] + red[1] + red[2] + red[3];
    const float tq = red[4] + red[5] + red[6] + red[7];
    const float mean = ts * (1.0f / N_EMBD);
    const float var  = tq * (1.0f / N_EMBD) - mean * mean;
    const float rs = rsqrtf(var + 1e-5f);
    float4 wv = ((const float4*)w)[t];
    float4 bv = ((const float4*)bias)[t];
    float4 o;
    o.x = (v.x - mean) * rs * wv.x + bv.x;
    o.y = (v.y - mean) * rs * wv.y + bv.y;
    o.z = (v.z - mean) * rs * wv.z + bv.z;
    o.w = (v.w - mean) * rs * wv.w + bv.w;
    ((float4*)p)[t] = o;
}

// ---------------------------------------------------------------------------
extern "C" void kernel_launch(void* const* d_in, const int* in_sizes, int n_in,
                              void* d_out, int out_size, void* d_ws, size_t ws_size,
                              hipStream_t stream) {
    const float* x  = (const float*)d_in[0];
    const float* W  = (const float*)d_in[1];
    const float* bq = (const float*)d_in[2];
    const float* lw = (const float*)d_in[3];
    const float* lb = (const float*)d_in[4];
    float* out = (float*)d_out;
    char* ws = (char*)d_ws;

    // workspace layout (bytes):
    //  Xb   @ 0          16,777,216  (8192x1024 bf16) — dead after GEMM
    //  Sbuf @ 0           5,242,880  (4*32*5 blocks of 64x64 bf16) — aliases Xb
    //  WbT  @ 16,777,216  6,291,456  (3072x1024 bf16)
    //  QK   @ 23,068,672 33,554,432  (8192x2048 bf16)
    //  Vt   @ 56,623,104 16,777,216  (4x1024x2048 bf16)
    //  total 73,400,320
    unsigned short* Xb   = (unsigned short*)(ws + 0);
    unsigned short* Sbuf = (unsigned short*)(ws + 0);
    unsigned short* WbT  = (unsigned short*)(ws + 16777216);
    unsigned short* QK   = (unsigned short*)(ws + 23068672);
    unsigned short* Vt   = (unsigned short*)(ws + 56623104);

    k_prep   <<<11264, 256, 0, stream>>>(x, Xb, W, WbT);
    k_gemm   <<<dim3(24, 64), 256, 0, stream>>>(Xb, WbT, bq, QK, Vt);
    k_scores <<<640,   256, 0, stream>>>(QK, Sbuf);
    k_sv     <<<1024,  256, 0, stream>>>(Sbuf, Vt, out);
    k_ln     <<<8192,  256, 0, stream>>>(out, lw, lb);
}